// Round 13
// baseline (412.914 us; speedup 1.0000x reference)
//
#include <hip/hip_runtime.h>

#define NF 128

typedef __attribute__((ext_vector_type(8))) short short8v;
typedef __attribute__((ext_vector_type(4))) float f32x4;

__device__ __forceinline__ unsigned short f2bf(float x) {
  unsigned u = __builtin_bit_cast(unsigned, x);
  unsigned r = (u + 0x7FFFu + ((u >> 16) & 1u)) >> 16;
  return (unsigned short)r;
}
__device__ __forceinline__ float bf2f(unsigned short h) {
  unsigned u = ((unsigned)h) << 16;
  return __builtin_bit_cast(float, u);
}
// unpack 4 bf16 (packed in uint2) -> float4
__device__ __forceinline__ float4 bfx4(uint2 v) {
  float4 r;
  r.x = __builtin_bit_cast(float, v.x << 16);
  r.y = __builtin_bit_cast(float, v.x & 0xffff0000u);
  r.z = __builtin_bit_cast(float, v.y << 16);
  r.w = __builtin_bit_cast(float, v.y & 0xffff0000u);
  return r;
}
__device__ __forceinline__ uint2 packbf4(float4 o) {
  uint2 p;
  p.x = (unsigned)f2bf(o.x) | ((unsigned)f2bf(o.y) << 16);
  p.y = (unsigned)f2bf(o.z) | ((unsigned)f2bf(o.w) << 16);
  return p;
}

// ---------------- zero cnt + dtype detect (merged) ----------------
__global__ void init_detect_k(const void* __restrict__ ei, int n_check, int N,
                              int* __restrict__ flag, int* __restrict__ cnt) {
  int i = blockIdx.x * blockDim.x + threadIdx.x;
  if (i < N) cnt[i] = 0;
  if (blockIdx.x == 0) {
    __shared__ int c;
    if (threadIdx.x == 0) c = 0;
    __syncthreads();
    const long long* p = (const long long*)ei;
    int good = 0;
    for (int k = threadIdx.x; k < n_check; k += blockDim.x) {
      long long v = p[k];
      if (v >= 0 && v < (long long)N) good++;
    }
    atomicAdd(&c, good);
    __syncthreads();
    if (threadIdx.x == 0) flag[0] = (c > n_check / 2) ? 1 : 0;
  }
}

// ------- decode + degree histogram (fused); writes packed (src,dst) pairs -------
__global__ void decode_hist_k(const void* __restrict__ ei, int E, int N,
                              const int* __restrict__ flag,
                              uint2* __restrict__ pd, int* __restrict__ cnt) {
  int is64 = flag[0];
  int stride = gridDim.x * blockDim.x;
  for (int e = blockIdx.x * blockDim.x + threadIdx.x; e < E; e += stride) {
    int s, d;
    if (is64) {
      s = (int)((const long long*)ei)[e];
      d = (int)((const long long*)ei)[(size_t)E + e];
    } else {
      s = ((const int*)ei)[e];
      d = ((const int*)ei)[(size_t)E + e];
    }
    s = min(max(s, 0), N - 1);
    d = min(max(d, 0), N - 1);
    uint2 p; p.x = (unsigned)s; p.y = (unsigned)d;
    pd[e] = p;
    atomicAdd(&cnt[d], 1);
  }
}

// ---------------- scan for CSR rowptr ----------------
__global__ __launch_bounds__(256) void scan_block_k(const int* __restrict__ cnt,
                                                    int* __restrict__ rowptr,
                                                    int* __restrict__ bsum, int N) {
  __shared__ int tmp[256];
  int i = blockIdx.x * 256 + threadIdx.x;
  int v = (i < N) ? cnt[i] : 0;
  tmp[threadIdx.x] = v;
  __syncthreads();
  for (int o = 1; o < 256; o <<= 1) {
    int t = (threadIdx.x >= o) ? tmp[threadIdx.x - o] : 0;
    __syncthreads();
    tmp[threadIdx.x] += t;
    __syncthreads();
  }
  if (i < N) rowptr[i] = tmp[threadIdx.x] - v;  // exclusive
  if (threadIdx.x == 255) bsum[blockIdx.x] = tmp[255];
}

__global__ __launch_bounds__(512) void scan_top_k(int* __restrict__ bsum, int nb) {
  __shared__ int tmp[512];
  int v = (threadIdx.x < nb) ? bsum[threadIdx.x] : 0;
  tmp[threadIdx.x] = v;
  __syncthreads();
  for (int o = 1; o < 512; o <<= 1) {
    int t = (threadIdx.x >= o) ? tmp[threadIdx.x - o] : 0;
    __syncthreads();
    tmp[threadIdx.x] += t;
    __syncthreads();
  }
  if (threadIdx.x < nb) bsum[threadIdx.x] = tmp[threadIdx.x] - v;  // exclusive
}

// ---- scan finalize + cursor init + dinv; extra blocks pack W1/W2 (hi/lo bf16) ----
__global__ void scan_add_k(int* __restrict__ rowptr, const int* __restrict__ bsum,
                           int* __restrict__ cursor, const int* __restrict__ cnt,
                           float* __restrict__ dinv, int N, int E, int nblk,
                           const float* __restrict__ W1, const float* __restrict__ W2,
                           unsigned short* __restrict__ PH1, unsigned short* __restrict__ PL1,
                           unsigned short* __restrict__ PH2, unsigned short* __restrict__ PL2) {
  if ((int)blockIdx.x < nblk) {
    int i = blockIdx.x * blockDim.x + threadIdx.x;
    if (i < N) {
      int r = rowptr[i] + bsum[i >> 8];
      rowptr[i] = r;
      cursor[i] = r;
      dinv[i] = rsqrtf((float)cnt[i] + 1.0f);  // +1 self-loop
    }
    if (i == 0) rowptr[N] = E;
  } else {
    // weight packing: frag-lane t in [0,4096)
    int t = (blockIdx.x - nblk) * blockDim.x + threadIdx.x;
    if (t >= 4096) return;
    const float* W = (t < 2048) ? W1 : W2;
    unsigned short* PH = (t < 2048) ? PH1 : PH2;
    unsigned short* PL = (t < 2048) ? PL1 : PL2;
    int tt = t & 2047;
    int ct = tt >> 8, kc = (tt >> 6) & 3, lane = tt & 63;
    int k0 = kc * 32 + 8 * (lane >> 4);
    int col = ct * 16 + (lane & 15);
#pragma unroll
    for (int e = 0; e < 8; ++e) {
      float w = W[(size_t)(k0 + e) * NF + col];
      unsigned short h = f2bf(w);
      float lo = w - bf2f(h);
      PH[(size_t)tt * 8 + e] = h;
      PL[(size_t)tt * 8 + e] = f2bf(lo);
    }
  }
}

// ---- 8-team fill over packed pairs: team t (blockIdx&7) fills dst range [t*R,(t+1)*R) ----
__global__ void fill_k(const uint2* __restrict__ pd,
                       int* __restrict__ cursor, int* __restrict__ csr, int E, int N) {
  int team = blockIdx.x & 7;
  int R = (N + 7) >> 3;
  int lo = team * R;
  int hi = min(N, lo + R);
  int sub = blockIdx.x >> 3;
  int nsub = gridDim.x >> 3;
  int stride = nsub * blockDim.x;
  int E2 = (E + 1) >> 1;
  const uint4* pd4 = (const uint4*)pd;
  for (int e2 = sub * blockDim.x + threadIdx.x; e2 < E2; e2 += stride) {
    if (2 * e2 + 1 < E) {
      uint4 v = pd4[e2];  // (s0,d0,s1,d1)
      int d0 = (int)v.y, d1 = (int)v.w;
      if (d0 >= lo && d0 < hi) {
        int pos = atomicAdd(&cursor[d0], 1);
        csr[pos] = (int)v.x;
      }
      if (d1 >= lo && d1 < hi) {
        int pos = atomicAdd(&cursor[d1], 1);
        csr[pos] = (int)v.z;
      }
    } else {
      uint2 v = pd[2 * e2];
      int d0 = (int)v.y;
      if (d0 >= lo && d0 < hi) {
        int pos = atomicAdd(&cursor[d0], 1);
        csr[pos] = (int)v.x;
      }
    }
  }
}

// ------- MFMA matmul (fp32 in): Yb[r,c] = bf16((X @ W)[r,c] * dinv[r]), bf16x3 -------
__global__ __launch_bounds__(256) void mm_mfma_k(const float* __restrict__ X,
                                                 const unsigned short* __restrict__ WPH,
                                                 const unsigned short* __restrict__ WPL,
                                                 const float* __restrict__ dinv,
                                                 unsigned short* __restrict__ Yb, int N) {
  int lane = threadIdx.x & 63;
  int wv = threadIdx.x >> 6;
  int row0 = blockIdx.x * 64 + wv * 16;
  if (row0 >= N) return;
  int ar = min(row0 + (lane & 15), N - 1);
  const float* xp = X + (size_t)ar * NF + 8 * (lane >> 4);
  short8v Ah[4], Al[4];
#pragma unroll
  for (int kc = 0; kc < 4; ++kc) {
    float4 v0 = *(const float4*)(xp + kc * 32);
    float4 v1 = *(const float4*)(xp + kc * 32 + 4);
    float xv[8] = {v0.x, v0.y, v0.z, v0.w, v1.x, v1.y, v1.z, v1.w};
#pragma unroll
    for (int e = 0; e < 8; ++e) {
      unsigned short h = f2bf(xv[e]);
      float lo = xv[e] - bf2f(h);
      Ah[kc][e] = (short)h;
      Al[kc][e] = (short)f2bf(lo);
    }
  }
  int rbase = row0 + (lane >> 4) * 4;
  float dv[4];
#pragma unroll
  for (int j = 0; j < 4; ++j) dv[j] = (rbase + j < N) ? dinv[rbase + j] : 0.f;
  const short8v* BH = (const short8v*)WPH;
  const short8v* BL = (const short8v*)WPL;
  int c = (lane & 15);
#pragma unroll
  for (int ct = 0; ct < 8; ++ct) {
    f32x4 acc = {0.f, 0.f, 0.f, 0.f};
#pragma unroll
    for (int kc = 0; kc < 4; ++kc) {
      short8v bh = BH[(ct * 4 + kc) * 64 + lane];
      short8v bl = BL[(ct * 4 + kc) * 64 + lane];
      acc = __builtin_amdgcn_mfma_f32_16x16x32_bf16(Ah[kc], bh, acc, 0, 0, 0);
      acc = __builtin_amdgcn_mfma_f32_16x16x32_bf16(Ah[kc], bl, acc, 0, 0, 0);
      acc = __builtin_amdgcn_mfma_f32_16x16x32_bf16(Al[kc], bh, acc, 0, 0, 0);
    }
#pragma unroll
    for (int j = 0; j < 4; ++j) {
      int r = rbase + j;
      if (r < N) Yb[(size_t)r * NF + ct * 16 + c] = f2bf(acc[j] * dv[j]);
    }
  }
}

// ------- MFMA matmul (bf16 in): A already bf16 -> no lo-split, 2 MFMAs/tile -------
__global__ __launch_bounds__(256) void mm_mfma_b_k(const unsigned short* __restrict__ Xb,
                                                   const unsigned short* __restrict__ WPH,
                                                   const unsigned short* __restrict__ WPL,
                                                   const float* __restrict__ dinv,
                                                   unsigned short* __restrict__ Yb, int N) {
  int lane = threadIdx.x & 63;
  int wv = threadIdx.x >> 6;
  int row0 = blockIdx.x * 64 + wv * 16;
  if (row0 >= N) return;
  int ar = min(row0 + (lane & 15), N - 1);
  const unsigned short* xp = Xb + (size_t)ar * NF + 8 * (lane >> 4);
  short8v Ah[4];
#pragma unroll
  for (int kc = 0; kc < 4; ++kc) Ah[kc] = *(const short8v*)(xp + kc * 32);
  int rbase = row0 + (lane >> 4) * 4;
  float dv[4];
#pragma unroll
  for (int j = 0; j < 4; ++j) dv[j] = (rbase + j < N) ? dinv[rbase + j] : 0.f;
  const short8v* BH = (const short8v*)WPH;
  const short8v* BL = (const short8v*)WPL;
  int c = (lane & 15);
#pragma unroll
  for (int ct = 0; ct < 8; ++ct) {
    f32x4 acc = {0.f, 0.f, 0.f, 0.f};
#pragma unroll
    for (int kc = 0; kc < 4; ++kc) {
      short8v bh = BH[(ct * 4 + kc) * 64 + lane];
      short8v bl = BL[(ct * 4 + kc) * 64 + lane];
      acc = __builtin_amdgcn_mfma_f32_16x16x32_bf16(Ah[kc], bh, acc, 0, 0, 0);
      acc = __builtin_amdgcn_mfma_f32_16x16x32_bf16(Ah[kc], bl, acc, 0, 0, 0);
    }
#pragma unroll
    for (int j = 0; j < 4; ++j) {
      int r = rbase + j;
      if (r < N) Yb[(size_t)r * NF + ct * 16 + c] = f2bf(acc[j] * dv[j]);
    }
  }
}

// ------- gather aggregate (bf16 G -> bf16 H): H[d,:] = relu(dinv[d]*(G[d,:]+sum G[s,:])+b) -------
__global__ __launch_bounds__(256) void gather_agg4_k(const int* __restrict__ rowptr,
                                                     const int* __restrict__ csr,
                                                     const float* __restrict__ dinv,
                                                     const unsigned short* __restrict__ G,
                                                     const float* __restrict__ b,
                                                     unsigned short* __restrict__ OUT, int N) {
  int lane = threadIdx.x & 63;
  int half = lane >> 5;
  int l32  = lane & 31;
  int w    = blockIdx.x * 4 + (threadIdx.x >> 6);
  int nw   = gridDim.x * 4;
  const uint2* G2 = (const uint2*)G;
  float4 bv = ((const float4*)b)[l32];
  for (int d0 = w * 2; d0 < N; d0 += nw * 2) {
    int d = d0 + half;
    if (d < N) {
      int beg = rowptr[d], end = rowptr[d + 1];
      float4 acc = bfx4(G2[(size_t)d * 32 + l32]);  // self-loop (already *dinv[d])
      int cnt = end - beg;
      int j = 0;
      while (j < cnt) {
        int chunk = min(cnt - j, 32);
        int idx = (l32 < chunk) ? csr[beg + j + l32] : 0;
        int t = 0;
        for (; t + 8 <= chunk; t += 8) {
          int s0 = __shfl(idx, t + 0, 32);
          int s1 = __shfl(idx, t + 1, 32);
          int s2 = __shfl(idx, t + 2, 32);
          int s3 = __shfl(idx, t + 3, 32);
          int s4 = __shfl(idx, t + 4, 32);
          int s5 = __shfl(idx, t + 5, 32);
          int s6 = __shfl(idx, t + 6, 32);
          int s7 = __shfl(idx, t + 7, 32);
          float4 v0 = bfx4(G2[(size_t)s0 * 32 + l32]);
          float4 v1 = bfx4(G2[(size_t)s1 * 32 + l32]);
          float4 v2 = bfx4(G2[(size_t)s2 * 32 + l32]);
          float4 v3 = bfx4(G2[(size_t)s3 * 32 + l32]);
          float4 v4 = bfx4(G2[(size_t)s4 * 32 + l32]);
          float4 v5 = bfx4(G2[(size_t)s5 * 32 + l32]);
          float4 v6 = bfx4(G2[(size_t)s6 * 32 + l32]);
          float4 v7 = bfx4(G2[(size_t)s7 * 32 + l32]);
          acc.x += (v0.x + v1.x) + (v2.x + v3.x) + ((v4.x + v5.x) + (v6.x + v7.x));
          acc.y += (v0.y + v1.y) + (v2.y + v3.y) + ((v4.y + v5.y) + (v6.y + v7.y));
          acc.z += (v0.z + v1.z) + (v2.z + v3.z) + ((v4.z + v5.z) + (v6.z + v7.z));
          acc.w += (v0.w + v1.w) + (v2.w + v3.w) + ((v4.w + v5.w) + (v6.w + v7.w));
        }
        for (; t < chunk; ++t) {
          int s = __shfl(idx, t, 32);
          float4 v = bfx4(G2[(size_t)s * 32 + l32]);
          acc.x += v.x; acc.y += v.y; acc.z += v.z; acc.w += v.w;
        }
        j += chunk;
      }
      float dd = dinv[d];
      float4 o;
      o.x = fmaxf(acc.x * dd + bv.x, 0.f);
      o.y = fmaxf(acc.y * dd + bv.y, 0.f);
      o.z = fmaxf(acc.z * dd + bv.z, 0.f);
      o.w = fmaxf(acc.w * dd + bv.w, 0.f);
      ((uint2*)OUT)[(size_t)d * 32 + l32] = packbf4(o);
    }
  }
}

// ------- layer-2 gather (bf16 G) fused with final projection: out[d] = dot(relu(...), Wl) + bl -------
__global__ __launch_bounds__(256) void gather_final4_k(const int* __restrict__ rowptr,
                                                       const int* __restrict__ csr,
                                                       const float* __restrict__ dinv,
                                                       const unsigned short* __restrict__ G,
                                                       const float* __restrict__ b,
                                                       const float* __restrict__ Wl,
                                                       const float* __restrict__ bl,
                                                       float* __restrict__ out, int N) {
  int lane = threadIdx.x & 63;
  int half = lane >> 5;
  int l32  = lane & 31;
  int w    = blockIdx.x * 4 + (threadIdx.x >> 6);
  int nw   = gridDim.x * 4;
  const uint2* G2 = (const uint2*)G;
  float4 bv = ((const float4*)b)[l32];
  float4 wv = ((const float4*)Wl)[l32];
  float blv = bl[0];
  for (int d0 = w * 2; d0 < N; d0 += nw * 2) {
    int d = d0 + half;
    if (d < N) {
      int beg = rowptr[d], end = rowptr[d + 1];
      float4 acc = bfx4(G2[(size_t)d * 32 + l32]);
      int cnt = end - beg;
      int j = 0;
      while (j < cnt) {
        int chunk = min(cnt - j, 32);
        int idx = (l32 < chunk) ? csr[beg + j + l32] : 0;
        int t = 0;
        for (; t + 8 <= chunk; t += 8) {
          int s0 = __shfl(idx, t + 0, 32);
          int s1 = __shfl(idx, t + 1, 32);
          int s2 = __shfl(idx, t + 2, 32);
          int s3 = __shfl(idx, t + 3, 32);
          int s4 = __shfl(idx, t + 4, 32);
          int s5 = __shfl(idx, t + 5, 32);
          int s6 = __shfl(idx, t + 6, 32);
          int s7 = __shfl(idx, t + 7, 32);
          float4 v0 = bfx4(G2[(size_t)s0 * 32 + l32]);
          float4 v1 = bfx4(G2[(size_t)s1 * 32 + l32]);
          float4 v2 = bfx4(G2[(size_t)s2 * 32 + l32]);
          float4 v3 = bfx4(G2[(size_t)s3 * 32 + l32]);
          float4 v4 = bfx4(G2[(size_t)s4 * 32 + l32]);
          float4 v5 = bfx4(G2[(size_t)s5 * 32 + l32]);
          float4 v6 = bfx4(G2[(size_t)s6 * 32 + l32]);
          float4 v7 = bfx4(G2[(size_t)s7 * 32 + l32]);
          acc.x += (v0.x + v1.x) + (v2.x + v3.x) + ((v4.x + v5.x) + (v6.x + v7.x));
          acc.y += (v0.y + v1.y) + (v2.y + v3.y) + ((v4.y + v5.y) + (v6.y + v7.y));
          acc.z += (v0.z + v1.z) + (v2.z + v3.z) + ((v4.z + v5.z) + (v6.z + v7.z));
          acc.w += (v0.w + v1.w) + (v2.w + v3.w) + ((v4.w + v5.w) + (v6.w + v7.w));
        }
        for (; t < chunk; ++t) {
          int s = __shfl(idx, t, 32);
          float4 v = bfx4(G2[(size_t)s * 32 + l32]);
          acc.x += v.x; acc.y += v.y; acc.z += v.z; acc.w += v.w;
        }
        j += chunk;
      }
      float dd = dinv[d];
      float p = fmaxf(acc.x * dd + bv.x, 0.f) * wv.x
              + fmaxf(acc.y * dd + bv.y, 0.f) * wv.y
              + fmaxf(acc.z * dd + bv.z, 0.f) * wv.z
              + fmaxf(acc.w * dd + bv.w, 0.f) * wv.w;
#pragma unroll
      for (int off = 16; off; off >>= 1) p += __shfl_xor(p, off, 32);
      if (l32 == 0) out[d] = p + blv;
    }
  }
}

extern "C" void kernel_launch(void* const* d_in, const int* in_sizes, int n_in,
                              void* d_out, int out_size, void* d_ws, size_t ws_size,
                              hipStream_t stream) {
  const float* x  = (const float*)d_in[0];
  const void*  ei = d_in[1];
  const float* W1 = (const float*)d_in[2];
  const float* b1 = (const float*)d_in[3];
  const float* W2 = (const float*)d_in[4];
  const float* b2 = (const float*)d_in[5];
  const float* Wl = (const float*)d_in[6];
  const float* bl = (const float*)d_in[7];
  float* out = (float*)d_out;

  int N = in_sizes[0] / NF;
  int E = in_sizes[1] / 2;

  char* ws = (char*)d_ws;
  size_t off = 0;
  auto carve = [&](size_t bytes) {
    char* p = ws + off;
    off = (off + bytes + 255) & ~255ULL;
    return p;
  };
  uint2* pd     = (uint2*)carve((size_t)E * 8);
  int*   csr    = (int*)carve((size_t)E * 4);
  int*   cnt    = (int*)carve((size_t)N * 4);
  int*   rowptr = (int*)carve((size_t)(N + 1) * 4);
  int*   cursor = (int*)carve((size_t)N * 4);
  float* dnv    = (float*)carve((size_t)N * 4);
  int*   bsum   = (int*)carve((size_t)4096 * 4);
  int*   flag   = (int*)carve(4);
  unsigned short* W1h = (unsigned short*)carve(16384 * 2);
  unsigned short* W1l = (unsigned short*)carve(16384 * 2);
  unsigned short* W2h = (unsigned short*)carve(16384 * 2);
  unsigned short* W2l = (unsigned short*)carve(16384 * 2);
  unsigned short* bufG = (unsigned short*)carve((size_t)N * NF * 2);  // bf16 G
  unsigned short* bufH = (unsigned short*)carve((size_t)N * NF * 2);  // bf16 hidden

  int nblk = (N + 255) / 256;  // 391 for N=100000 (<=512 for scan_top)
  int mmblk = (N + 63) / 64;

  hipLaunchKernelGGL(init_detect_k, dim3(nblk), dim3(256), 0, stream, ei, 1024, N, flag, cnt);
  hipLaunchKernelGGL(decode_hist_k, dim3(2048), dim3(256), 0, stream, ei, E, N, flag, pd, cnt);

  // CSR build (+ weight packing folded into scan_add)
  hipLaunchKernelGGL(scan_block_k, dim3(nblk), dim3(256), 0, stream, cnt, rowptr, bsum, N);
  hipLaunchKernelGGL(scan_top_k, dim3(1), dim3(512), 0, stream, bsum, nblk);
  hipLaunchKernelGGL(scan_add_k, dim3(nblk + 16), dim3(256), 0, stream, rowptr, bsum, cursor,
                     cnt, dnv, N, E, nblk, W1, W2, W1h, W1l, W2h, W2l);
  hipLaunchKernelGGL(fill_k, dim3(2048), dim3(256), 0, stream, pd, cursor, csr, E, N);

  // layer 1
  hipLaunchKernelGGL(mm_mfma_k, dim3(mmblk), dim3(256), 0, stream, x, W1h, W1l, dnv, bufG, N);
  hipLaunchKernelGGL(gather_agg4_k, dim3(2048), dim3(256), 0, stream, rowptr, csr, dnv, bufG, b1, bufH, N);

  // layer 2 (+ fused final projection)
  hipLaunchKernelGGL(mm_mfma_b_k, dim3(mmblk), dim3(256), 0, stream, bufH, W2h, W2l, dnv, bufG, N);
  hipLaunchKernelGGL(gather_final4_k, dim3(2048), dim3(256), 0, stream, rowptr, csr, dnv, bufG, b2, Wl, bl, out, N);
}